// Round 1
// baseline (1536.104 us; speedup 1.0000x reference)
//
#include <hip/hip_runtime.h>

// WindowAttention: B_=4096, N=49, C=256, H=8, hd=32, nW=64
// ws layout (bf16): [q | k | v | pre] each SEG elements
//   q/k/v: (B_, H, N, hd) head-major, q pre-scaled by hd^-0.5
//   pre  : (B_, N, C) attention output before proj
#define SEG 51380224  // 4096*8*49*32 == 4096*49*256

typedef __attribute__((ext_vector_type(8))) __bf16 bf16x8;
typedef __attribute__((ext_vector_type(4))) __bf16 bf16x4;
typedef __attribute__((ext_vector_type(4))) float f32x4;

// ---------------------------------------------------------------------------
// K1: qkv = x @ qkv_w^T + qkv_b, scatter to q/k/v segments (bf16, head-major)
// M=200704 (=3136*64), K=256, N=768 (=12*64). 64x64 tile, 4 waves of 32x32.
// ---------------------------------------------------------------------------
__global__ __launch_bounds__(256)
void qkv_gemm_k(const float* __restrict__ x, const float* __restrict__ w,
                const float* __restrict__ bvec, __bf16* __restrict__ ws)
{
    __shared__ __bf16 As[64][72];  // +8 pad keeps 16B align, breaks bank stride
    __shared__ __bf16 Bs[64][72];  // Bs[n][k] = w[n0+n][k0+k] (B^T layout)
    const int tid  = threadIdx.x;
    const int m0   = blockIdx.x * 64;
    const int n0   = blockIdx.y * 64;
    const int wave = tid >> 6, lane = tid & 63;
    const int wm   = wave >> 1, wn = wave & 1;
    const int quad = lane >> 4, lm = lane & 15;

    f32x4 acc[2][2] = {};

    for (int k0 = 0; k0 < 256; k0 += 64) {
#pragma unroll
        for (int t = 0; t < 4; ++t) {
            int idx = tid + t * 256;             // 0..1023
            int r = idx >> 4, c4 = (idx & 15) << 2;
            float4 fa = *reinterpret_cast<const float4*>(x + (size_t)(m0 + r) * 256 + k0 + c4);
            bf16x4 ha = { (__bf16)fa.x, (__bf16)fa.y, (__bf16)fa.z, (__bf16)fa.w };
            *reinterpret_cast<bf16x4*>(&As[r][c4]) = ha;
            float4 fb = *reinterpret_cast<const float4*>(w + (size_t)(n0 + r) * 256 + k0 + c4);
            bf16x4 hb = { (__bf16)fb.x, (__bf16)fb.y, (__bf16)fb.z, (__bf16)fb.w };
            *reinterpret_cast<bf16x4*>(&Bs[r][c4]) = hb;
        }
        __syncthreads();
#pragma unroll
        for (int kk = 0; kk < 64; kk += 32) {
            bf16x8 a0 = *reinterpret_cast<const bf16x8*>(&As[wm*32      + lm][kk + quad*8]);
            bf16x8 a1 = *reinterpret_cast<const bf16x8*>(&As[wm*32 + 16 + lm][kk + quad*8]);
            bf16x8 b0 = *reinterpret_cast<const bf16x8*>(&Bs[wn*32      + lm][kk + quad*8]);
            bf16x8 b1 = *reinterpret_cast<const bf16x8*>(&Bs[wn*32 + 16 + lm][kk + quad*8]);
            acc[0][0] = __builtin_amdgcn_mfma_f32_16x16x32_bf16(a0, b0, acc[0][0], 0, 0, 0);
            acc[0][1] = __builtin_amdgcn_mfma_f32_16x16x32_bf16(a0, b1, acc[0][1], 0, 0, 0);
            acc[1][0] = __builtin_amdgcn_mfma_f32_16x16x32_bf16(a1, b0, acc[1][0], 0, 0, 0);
            acc[1][1] = __builtin_amdgcn_mfma_f32_16x16x32_bf16(a1, b1, acc[1][1], 0, 0, 0);
        }
        __syncthreads();
    }

#pragma unroll
    for (int mt = 0; mt < 2; ++mt)
#pragma unroll
        for (int nt = 0; nt < 2; ++nt) {
            int j  = n0 + wn*32 + nt*16 + lm;     // output col in [0,768)
            int c3 = j >> 8, hh = (j >> 5) & 7, d = j & 31;
            float bj  = bvec[j];
            float scl = (c3 == 0) ? 0.17677669529663687f : 1.0f;  // hd^-0.5 on q only
#pragma unroll
            for (int r = 0; r < 4; ++r) {
                int m = m0 + wm*32 + mt*16 + quad*4 + r;          // C/D row mapping
                int b = m / 49, nw = m - b * 49;
                float v = (acc[mt][nt][r] + bj) * scl;
                ws[(size_t)c3 * SEG + ((size_t)((b*8 + hh)*49 + nw))*32 + d] = (__bf16)v;
            }
        }
}

// ---------------------------------------------------------------------------
// K2: per (window, head): attn = softmax(q k^T + bias + mask); pre = attn @ v
// ---------------------------------------------------------------------------
__global__ __launch_bounds__(256)
void attn_k(const __bf16* __restrict__ ws, const float* __restrict__ mask,
            const float* __restrict__ rpb, __bf16* __restrict__ pre)
{
    __shared__ float qs[52*33], ks[52*33], vs[52*33];  // +1 col pad: bank spread
    __shared__ float at[52*51];                        // rows 49..51 scratch only
    __shared__ float bs[169];
    const int tid = threadIdx.x;
    const int bh  = blockIdx.x;            // b*8 + h
    const int b   = bh >> 3, h = bh & 7;

    const __bf16* qp = ws + (size_t)bh * (49*32);
    const __bf16* kp = qp + SEG;
    const __bf16* vp = qp + (size_t)2 * SEG;
    const float*  mp = mask + (size_t)(b & 63) * 2401;

    for (int p = tid; p < 2401; p += 256) at[(p/49)*51 + (p - (p/49)*49)] = mp[p];
    for (int p = tid; p < 1568; p += 256) {
        int i = p >> 5, d = p & 31;
        qs[i*33+d] = (float)qp[p];
        ks[i*33+d] = (float)kp[p];
        vs[i*33+d] = (float)vp[p];
    }
    for (int p = tid; p < 169; p += 256) bs[p] = rpb[p*8 + h];
    __syncthreads();

    // Phase B: 4x4-register-tiled q.k^T; mask already in at[], add bias here
    if (tid < 169) {
        int ti = tid / 13, tj = tid - ti*13;
        int i0 = ti*4, j0 = tj*4;
        float acc[4][4] = {};
#pragma unroll 8
        for (int kk = 0; kk < 32; ++kk) {
            float qv[4], kv[4];
#pragma unroll
            for (int r = 0; r < 4; ++r) qv[r] = qs[(i0+r)*33 + kk];
#pragma unroll
            for (int c = 0; c < 4; ++c) kv[c] = ks[(j0+c)*33 + kk];
#pragma unroll
            for (int r = 0; r < 4; ++r)
#pragma unroll
                for (int c = 0; c < 4; ++c) acc[r][c] += qv[r]*kv[c];
        }
#pragma unroll
        for (int r = 0; r < 4; ++r) {
            int i = i0 + r; if (i >= 49) break;
            int ih = i/7, iw = i - ih*7;
#pragma unroll
            for (int c = 0; c < 4; ++c) {
                int j = j0 + c; if (j >= 49) continue;
                int jh = j/7, jw = j - jh*7;
                int bidx = (ih - jh + 6)*13 + (iw - jw + 6);
                at[i*51 + j] += acc[r][c] + bs[bidx];
            }
        }
    }
    __syncthreads();

    // Phase C: softmax, 4 lanes per row (lane-aligned groups -> shfl_xor ok)
    {
        int g = tid >> 2, l = tid & 3;
        if (g < 49) {
            float mx = -1e30f;
            for (int j = l; j < 49; j += 4) mx = fmaxf(mx, at[g*51+j]);
            mx = fmaxf(mx, __shfl_xor(mx, 1));
            mx = fmaxf(mx, __shfl_xor(mx, 2));
            float s = 0.f;
            for (int j = l; j < 49; j += 4) {
                float e = __expf(at[g*51+j] - mx);
                at[g*51+j] = e; s += e;
            }
            s += __shfl_xor(s, 1);
            s += __shfl_xor(s, 2);
            float rs = 1.0f / s;
            for (int j = l; j < 49; j += 4) at[g*51+j] *= rs;
        }
    }
    __syncthreads();

    // Phase D: pre = attn @ v, 4x4 register tiles (13 x 8 = 104 threads)
    if (tid < 104) {
        int ti = tid >> 3, td = tid & 7;
        int i0 = ti*4, d0 = td*4;
        float acc[4][4] = {};
        for (int j = 0; j < 49; ++j) {
            float av[4], vv[4];
#pragma unroll
            for (int r = 0; r < 4; ++r) av[r] = at[(i0+r)*51 + j];
#pragma unroll
            for (int c = 0; c < 4; ++c) vv[c] = vs[j*33 + d0 + c];
#pragma unroll
            for (int r = 0; r < 4; ++r)
#pragma unroll
                for (int c = 0; c < 4; ++c) acc[r][c] += av[r]*vv[c];
        }
#pragma unroll
        for (int r = 0; r < 4; ++r) {
            int i = i0 + r; if (i >= 49) break;
            size_t base = ((size_t)(b*49 + i))*256 + h*32 + d0;
#pragma unroll
            for (int c = 0; c < 4; ++c) pre[base + c] = (__bf16)acc[r][c];
        }
    }
}

// ---------------------------------------------------------------------------
// K3: out = pre @ proj_w^T + proj_b (fp32 out). M=200704, K=256, N=256.
// ---------------------------------------------------------------------------
__global__ __launch_bounds__(256)
void proj_gemm_k(const __bf16* __restrict__ pre, const float* __restrict__ w,
                 const float* __restrict__ bvec, float* __restrict__ out)
{
    __shared__ __bf16 As[64][72];
    __shared__ __bf16 Bs[64][72];
    const int tid  = threadIdx.x;
    const int m0   = blockIdx.x * 64;
    const int n0   = blockIdx.y * 64;
    const int wave = tid >> 6, lane = tid & 63;
    const int wm   = wave >> 1, wn = wave & 1;
    const int quad = lane >> 4, lm = lane & 15;

    f32x4 acc[2][2] = {};

    for (int k0 = 0; k0 < 256; k0 += 64) {
#pragma unroll
        for (int t = 0; t < 2; ++t) {            // A tile already bf16
            int g = tid + t*256;                 // 0..511 groups of 8
            int r = g >> 3, c8 = (g & 7) << 3;
            *reinterpret_cast<bf16x8*>(&As[r][c8]) =
                *reinterpret_cast<const bf16x8*>(pre + (size_t)(m0 + r)*256 + k0 + c8);
        }
#pragma unroll
        for (int t = 0; t < 4; ++t) {            // B from fp32 proj_w
            int idx = tid + t*256;
            int r = idx >> 4, c4 = (idx & 15) << 2;
            float4 fb = *reinterpret_cast<const float4*>(w + (size_t)(n0 + r)*256 + k0 + c4);
            bf16x4 hb = { (__bf16)fb.x, (__bf16)fb.y, (__bf16)fb.z, (__bf16)fb.w };
            *reinterpret_cast<bf16x4*>(&Bs[r][c4]) = hb;
        }
        __syncthreads();
#pragma unroll
        for (int kk = 0; kk < 64; kk += 32) {
            bf16x8 a0 = *reinterpret_cast<const bf16x8*>(&As[wm*32      + lm][kk + quad*8]);
            bf16x8 a1 = *reinterpret_cast<const bf16x8*>(&As[wm*32 + 16 + lm][kk + quad*8]);
            bf16x8 b0 = *reinterpret_cast<const bf16x8*>(&Bs[wn*32      + lm][kk + quad*8]);
            bf16x8 b1 = *reinterpret_cast<const bf16x8*>(&Bs[wn*32 + 16 + lm][kk + quad*8]);
            acc[0][0] = __builtin_amdgcn_mfma_f32_16x16x32_bf16(a0, b0, acc[0][0], 0, 0, 0);
            acc[0][1] = __builtin_amdgcn_mfma_f32_16x16x32_bf16(a0, b1, acc[0][1], 0, 0, 0);
            acc[1][0] = __builtin_amdgcn_mfma_f32_16x16x32_bf16(a1, b0, acc[1][0], 0, 0, 0);
            acc[1][1] = __builtin_amdgcn_mfma_f32_16x16x32_bf16(a1, b1, acc[1][1], 0, 0, 0);
        }
        __syncthreads();
    }

#pragma unroll
    for (int mt = 0; mt < 2; ++mt)
#pragma unroll
        for (int nt = 0; nt < 2; ++nt) {
            int j = n0 + wn*32 + nt*16 + lm;
            float bj = bvec[j];
#pragma unroll
            for (int r = 0; r < 4; ++r) {
                int m = m0 + wm*32 + mt*16 + quad*4 + r;
                out[(size_t)m*256 + j] = acc[mt][nt][r] + bj;
            }
        }
}

extern "C" void kernel_launch(void* const* d_in, const int* in_sizes, int n_in,
                              void* d_out, int out_size, void* d_ws, size_t ws_size,
                              hipStream_t stream)
{
    const float* x      = (const float*)d_in[0];
    const float* mask   = (const float*)d_in[1];
    const float* qkv_w  = (const float*)d_in[2];
    const float* qkv_b  = (const float*)d_in[3];
    const float* proj_w = (const float*)d_in[4];
    const float* proj_b = (const float*)d_in[5];
    const float* rpb    = (const float*)d_in[6];

    __bf16* ws  = (__bf16*)d_ws;                 // needs 4*SEG*2 = 411 MB
    __bf16* pre = ws + (size_t)3 * SEG;
    float*  out = (float*)d_out;

    qkv_gemm_k<<<dim3(3136, 12), 256, 0, stream>>>(x, qkv_w, qkv_b, ws);
    attn_k<<<dim3(32768), 256, 0, stream>>>(ws, mask, rpb, pre);
    proj_gemm_k<<<dim3(3136, 4), 256, 0, stream>>>(pre, proj_w, proj_b, out);
}

// Round 2
// 914.806 us; speedup vs baseline: 1.6792x; 1.6792x over previous
//
#include <hip/hip_runtime.h>

// WindowAttention: B_=4096, N=49, C=256, H=8, hd=32, nW=64
// ws layout (bf16): [q | k | v | pre] each SEG elements
//   q/k/v: (B_, H, N, hd) head-major, q pre-scaled by hd^-0.5
//   pre  : (B_, N, C) attention output before proj
// d_out doubles as scratch for the expanded (mask+bias) tensor ADD
// (nW*H, 64, 64) fp32 = 8.4 MB; proj_gemm fully overwrites d_out afterwards.
#define SEG 51380224  // 4096*8*49*32 == 4096*49*256

typedef __attribute__((ext_vector_type(8))) __bf16 bf16x8;
typedef __attribute__((ext_vector_type(4))) __bf16 bf16x4;
typedef __attribute__((ext_vector_type(4))) float f32x4;

static __device__ __forceinline__ bf16x8 bzero8() {
    bf16x8 z;
#pragma unroll
    for (int u = 0; u < 8; ++u) z[u] = (__bf16)0.0f;
    return z;
}

// ---------------------------------------------------------------------------
// K0: ADD[w*8+h][i][j] = mask[w][i][j] + bias[h][i][j]  (64x64, -1e30 pad)
// ---------------------------------------------------------------------------
__global__ __launch_bounds__(256)
void expand_add_k(const float* __restrict__ mask, const float* __restrict__ rpb,
                  float* __restrict__ add)
{
    const int wh = blockIdx.x;           // 0..511
    const int w = wh >> 3, h = wh & 7;
    for (int e = threadIdx.x; e < 4096; e += 256) {
        int i = e >> 6, j = e & 63;
        float v = -1e30f;
        if (i < 49 && j < 49) {
            int ih = i / 7, iw = i - ih * 7;
            int jh = j / 7, jw = j - jh * 7;
            int bidx = (ih - jh + 6) * 13 + (iw - jw + 6);
            v = mask[(size_t)w * 2401 + i * 49 + j] + rpb[bidx * 8 + h];
        }
        add[(size_t)wh * 4096 + e] = v;
    }
}

// ---------------------------------------------------------------------------
// K1: qkv = x @ qkv_w^T + qkv_b, scatter to q/k/v segments (bf16, head-major)
// ---------------------------------------------------------------------------
__global__ __launch_bounds__(256)
void qkv_gemm_k(const float* __restrict__ x, const float* __restrict__ w,
                const float* __restrict__ bvec, __bf16* __restrict__ ws)
{
    __shared__ __bf16 As[64][72];
    __shared__ __bf16 Bs[64][72];
    const int tid  = threadIdx.x;
    const int m0   = blockIdx.x * 64;
    const int n0   = blockIdx.y * 64;
    const int wave = tid >> 6, lane = tid & 63;
    const int wm   = wave >> 1, wn = wave & 1;
    const int quad = lane >> 4, lm = lane & 15;

    f32x4 acc[2][2] = {};

    for (int k0 = 0; k0 < 256; k0 += 64) {
#pragma unroll
        for (int t = 0; t < 4; ++t) {
            int idx = tid + t * 256;
            int r = idx >> 4, c4 = (idx & 15) << 2;
            float4 fa = *reinterpret_cast<const float4*>(x + (size_t)(m0 + r) * 256 + k0 + c4);
            bf16x4 ha = { (__bf16)fa.x, (__bf16)fa.y, (__bf16)fa.z, (__bf16)fa.w };
            *reinterpret_cast<bf16x4*>(&As[r][c4]) = ha;
            float4 fb = *reinterpret_cast<const float4*>(w + (size_t)(n0 + r) * 256 + k0 + c4);
            bf16x4 hb = { (__bf16)fb.x, (__bf16)fb.y, (__bf16)fb.z, (__bf16)fb.w };
            *reinterpret_cast<bf16x4*>(&Bs[r][c4]) = hb;
        }
        __syncthreads();
#pragma unroll
        for (int kk = 0; kk < 64; kk += 32) {
            bf16x8 a0 = *reinterpret_cast<const bf16x8*>(&As[wm*32      + lm][kk + quad*8]);
            bf16x8 a1 = *reinterpret_cast<const bf16x8*>(&As[wm*32 + 16 + lm][kk + quad*8]);
            bf16x8 b0 = *reinterpret_cast<const bf16x8*>(&Bs[wn*32      + lm][kk + quad*8]);
            bf16x8 b1 = *reinterpret_cast<const bf16x8*>(&Bs[wn*32 + 16 + lm][kk + quad*8]);
            acc[0][0] = __builtin_amdgcn_mfma_f32_16x16x32_bf16(a0, b0, acc[0][0], 0, 0, 0);
            acc[0][1] = __builtin_amdgcn_mfma_f32_16x16x32_bf16(a0, b1, acc[0][1], 0, 0, 0);
            acc[1][0] = __builtin_amdgcn_mfma_f32_16x16x32_bf16(a1, b0, acc[1][0], 0, 0, 0);
            acc[1][1] = __builtin_amdgcn_mfma_f32_16x16x32_bf16(a1, b1, acc[1][1], 0, 0, 0);
        }
        __syncthreads();
    }

#pragma unroll
    for (int mt = 0; mt < 2; ++mt)
#pragma unroll
        for (int nt = 0; nt < 2; ++nt) {
            int j  = n0 + wn*32 + nt*16 + lm;
            int c3 = j >> 8, hh = (j >> 5) & 7, d = j & 31;
            float bj  = bvec[j];
            float scl = (c3 == 0) ? 0.17677669529663687f : 1.0f;
#pragma unroll
            for (int r = 0; r < 4; ++r) {
                int m = m0 + wm*32 + mt*16 + quad*4 + r;
                int b = m / 49, nw = m - b * 49;
                float v = (acc[mt][nt][r] + bj) * scl;
                ws[(size_t)c3 * SEG + ((size_t)((b*8 + hh)*49 + nw))*32 + d] = (__bf16)v;
            }
        }
}

// ---------------------------------------------------------------------------
// K2: MFMA attention. One wave (64 threads) per (window, head).
//   S^T = K·Q^T (16 mfma) -> +ADD -> in-register softmax -> P to LDS (bf16)
//   -> out = P·V (16 mfma, V transposed into LDS) -> pre (B_,N,C) bf16.
// ---------------------------------------------------------------------------
__global__ __launch_bounds__(64)
void attn_mfma_k(const __bf16* __restrict__ ws, const float* __restrict__ add,
                 __bf16* __restrict__ pre)
{
    __shared__ __bf16 Pl[64 * 72];   // P[i][j], row stride 72 (2-way bank alias = free)
    __shared__ __bf16 Vt[32 * 72];   // V^T[d][j]
    const int lane = threadIdx.x;
    const int bh   = blockIdx.x;                 // b*8 + h
    const int b    = bh >> 3, h = bh & 7;
    const int wh   = ((b & 63) << 3) | h;
    const int quad = lane >> 4, lm = lane & 15;
    const int koff = quad * 8;

    const __bf16* qp = ws + (size_t)bh * (49 * 32);
    const __bf16* kp = qp + SEG;
    const __bf16* vp = qp + (size_t)2 * SEG;

    // ---- zero V^T pad rows j=48..63 (j=48 overwritten below; j>=49 must be
    // exactly representable-finite so P(=0)*Vt can't make NaN)
    {
        int d = lane >> 1, j0 = 48 + (lane & 1) * 8;
        *reinterpret_cast<bf16x8*>(&Vt[d * 72 + j0]) = bzero8();
    }
    // ---- transpose V (49x32) into Vt
#pragma unroll
    for (int t = 0; t < 4; ++t) {
        int idx = lane + t * 64;
        if (idx < 196) {
            int j = idx >> 2, c8 = (idx & 3) * 8;
            bf16x8 vv = *reinterpret_cast<const bf16x8*>(vp + j * 32 + c8);
#pragma unroll
            for (int u = 0; u < 8; ++u) Vt[(c8 + u) * 72 + j] = vv[u];
        }
    }

    // ---- Q (B-operand, col=i) unpredicated; K (A-operand, row=j) zero-padded
    bf16x8 qf[4], kf[4];
#pragma unroll
    for (int t = 0; t < 4; ++t)
        qf[t] = *reinterpret_cast<const bf16x8*>(qp + (t * 16 + lm) * 32 + koff);
#pragma unroll
    for (int t = 0; t < 4; ++t) {
        int m = t * 16 + lm;
        kf[t] = (m < 49) ? *reinterpret_cast<const bf16x8*>(kp + m * 32 + koff)
                         : bzero8();
    }

    // ---- S^T = K·Q^T : s[mt][nt], rows j = mt*16+quad*4+r, cols i = nt*16+lm
    f32x4 s[4][4] = {};
#pragma unroll
    for (int mt = 0; mt < 4; ++mt)
#pragma unroll
        for (int nt = 0; nt < 4; ++nt)
            s[mt][nt] = __builtin_amdgcn_mfma_f32_16x16x32_bf16(kf[mt], qf[nt], s[mt][nt], 0, 0, 0);

    // ---- + (mask+bias), layout ADD[wh][i][j]: regs = 4 consecutive j
    const float* ap = add + (size_t)wh * 4096;
#pragma unroll
    for (int nt = 0; nt < 4; ++nt) {
        int i = nt * 16 + lm;
#pragma unroll
        for (int mt = 0; mt < 4; ++mt) {
            f32x4 a4 = *reinterpret_cast<const f32x4*>(ap + i * 64 + mt * 16 + quad * 4);
            s[mt][nt] += a4;
        }
    }

    // ---- softmax over j (rows of S = i). Row i fixed per (nt,lm); j spread
    // over mt, reg, and quad -> in-register reduce + shfl_xor(16,32).
#pragma unroll
    for (int nt = 0; nt < 4; ++nt) {
        float mx = -3.0e38f;
#pragma unroll
        for (int mt = 0; mt < 4; ++mt)
#pragma unroll
            for (int r = 0; r < 4; ++r) mx = fmaxf(mx, s[mt][nt][r]);
        mx = fmaxf(mx, __shfl_xor(mx, 16));
        mx = fmaxf(mx, __shfl_xor(mx, 32));
        float sum = 0.f;
#pragma unroll
        for (int mt = 0; mt < 4; ++mt)
#pragma unroll
            for (int r = 0; r < 4; ++r) {
                float e = __expf(s[mt][nt][r] - mx);
                s[mt][nt][r] = e; sum += e;
            }
        sum += __shfl_xor(sum, 16);
        sum += __shfl_xor(sum, 32);
        float rl = 1.0f / sum;
#pragma unroll
        for (int mt = 0; mt < 4; ++mt)
#pragma unroll
            for (int r = 0; r < 4; ++r) s[mt][nt][r] *= rl;
    }

    // ---- P -> LDS, Pl[i][j]: 4 consecutive j per reg -> b64 stores
#pragma unroll
    for (int nt = 0; nt < 4; ++nt) {
        int i = nt * 16 + lm;
#pragma unroll
        for (int mt = 0; mt < 4; ++mt) {
            bf16x4 p4;
#pragma unroll
            for (int r = 0; r < 4; ++r) p4[r] = (__bf16)s[mt][nt][r];
            *reinterpret_cast<bf16x4*>(&Pl[i * 72 + mt * 16 + quad * 4]) = p4;
        }
    }
    __syncthreads();

    // ---- out = P·V : A = P rows i (ds_read_b128), B = V^T rows d
    f32x4 o[4][2] = {};
#pragma unroll
    for (int kt = 0; kt < 2; ++kt) {
        bf16x8 vf[2];
#pragma unroll
        for (int dt = 0; dt < 2; ++dt)
            vf[dt] = *reinterpret_cast<const bf16x8*>(&Vt[(dt * 16 + lm) * 72 + kt * 32 + koff]);
#pragma unroll
        for (int mt2 = 0; mt2 < 4; ++mt2) {
            bf16x8 pf = *reinterpret_cast<const bf16x8*>(&Pl[(mt2 * 16 + lm) * 72 + kt * 32 + koff]);
#pragma unroll
            for (int dt = 0; dt < 2; ++dt)
                o[mt2][dt] = __builtin_amdgcn_mfma_f32_16x16x32_bf16(pf, vf[dt], o[mt2][dt], 0, 0, 0);
        }
    }

    // ---- store pre (B_,N,C): row i = mt2*16+quad*4+r, col = h*32 + dt*16+lm
#pragma unroll
    for (int mt2 = 0; mt2 < 4; ++mt2) {
        int ib = mt2 * 16 + quad * 4;
#pragma unroll
        for (int r = 0; r < 4; ++r) {
            int i = ib + r;
            if (i < 49) {
                size_t base = ((size_t)(b * 49 + i)) * 256 + h * 32;
                pre[base + lm]      = (__bf16)o[mt2][0][r];
                pre[base + 16 + lm] = (__bf16)o[mt2][1][r];
            }
        }
    }
}

// ---------------------------------------------------------------------------
// K3: out = pre @ proj_w^T + proj_b (fp32 out). M=200704, K=256, N=256.
// ---------------------------------------------------------------------------
__global__ __launch_bounds__(256)
void proj_gemm_k(const __bf16* __restrict__ pre, const float* __restrict__ w,
                 const float* __restrict__ bvec, float* __restrict__ out)
{
    __shared__ __bf16 As[64][72];
    __shared__ __bf16 Bs[64][72];
    const int tid  = threadIdx.x;
    const int m0   = blockIdx.x * 64;
    const int n0   = blockIdx.y * 64;
    const int wave = tid >> 6, lane = tid & 63;
    const int wm   = wave >> 1, wn = wave & 1;
    const int quad = lane >> 4, lm = lane & 15;

    f32x4 acc[2][2] = {};

    for (int k0 = 0; k0 < 256; k0 += 64) {
#pragma unroll
        for (int t = 0; t < 2; ++t) {
            int g = tid + t * 256;
            int r = g >> 3, c8 = (g & 7) << 3;
            *reinterpret_cast<bf16x8*>(&As[r][c8]) =
                *reinterpret_cast<const bf16x8*>(pre + (size_t)(m0 + r) * 256 + k0 + c8);
        }
#pragma unroll
        for (int t = 0; t < 4; ++t) {
            int idx = tid + t * 256;
            int r = idx >> 4, c4 = (idx & 15) << 2;
            float4 fb = *reinterpret_cast<const float4*>(w + (size_t)(n0 + r) * 256 + k0 + c4);
            bf16x4 hb = { (__bf16)fb.x, (__bf16)fb.y, (__bf16)fb.z, (__bf16)fb.w };
            *reinterpret_cast<bf16x4*>(&Bs[r][c4]) = hb;
        }
        __syncthreads();
#pragma unroll
        for (int kk = 0; kk < 64; kk += 32) {
            bf16x8 a0 = *reinterpret_cast<const bf16x8*>(&As[wm*32      + lm][kk + quad*8]);
            bf16x8 a1 = *reinterpret_cast<const bf16x8*>(&As[wm*32 + 16 + lm][kk + quad*8]);
            bf16x8 b0 = *reinterpret_cast<const bf16x8*>(&Bs[wn*32      + lm][kk + quad*8]);
            bf16x8 b1 = *reinterpret_cast<const bf16x8*>(&Bs[wn*32 + 16 + lm][kk + quad*8]);
            acc[0][0] = __builtin_amdgcn_mfma_f32_16x16x32_bf16(a0, b0, acc[0][0], 0, 0, 0);
            acc[0][1] = __builtin_amdgcn_mfma_f32_16x16x32_bf16(a0, b1, acc[0][1], 0, 0, 0);
            acc[1][0] = __builtin_amdgcn_mfma_f32_16x16x32_bf16(a1, b0, acc[1][0], 0, 0, 0);
            acc[1][1] = __builtin_amdgcn_mfma_f32_16x16x32_bf16(a1, b1, acc[1][1], 0, 0, 0);
        }
        __syncthreads();
    }

#pragma unroll
    for (int mt = 0; mt < 2; ++mt)
#pragma unroll
        for (int nt = 0; nt < 2; ++nt) {
            int j = n0 + wn*32 + nt*16 + lm;
            float bj = bvec[j];
#pragma unroll
            for (int r = 0; r < 4; ++r) {
                int m = m0 + wm*32 + mt*16 + quad*4 + r;
                out[(size_t)m*256 + j] = acc[mt][nt][r] + bj;
            }
        }
}

extern "C" void kernel_launch(void* const* d_in, const int* in_sizes, int n_in,
                              void* d_out, int out_size, void* d_ws, size_t ws_size,
                              hipStream_t stream)
{
    const float* x      = (const float*)d_in[0];
    const float* mask   = (const float*)d_in[1];
    const float* qkv_w  = (const float*)d_in[2];
    const float* qkv_b  = (const float*)d_in[3];
    const float* proj_w = (const float*)d_in[4];
    const float* proj_b = (const float*)d_in[5];
    const float* rpb    = (const float*)d_in[6];

    __bf16* ws  = (__bf16*)d_ws;                 // 4*SEG*2 = 411 MB
    __bf16* pre = ws + (size_t)3 * SEG;
    float*  out = (float*)d_out;
    float*  addbuf = (float*)d_out;              // scratch; K3 overwrites all of d_out

    expand_add_k<<<dim3(512), 256, 0, stream>>>(mask, rpb, addbuf);
    qkv_gemm_k<<<dim3(3136, 12), 256, 0, stream>>>(x, qkv_w, qkv_b, ws);
    attn_mfma_k<<<dim3(32768), 64, 0, stream>>>(ws, addbuf, pre);
    proj_gemm_k<<<dim3(3136, 4), 256, 0, stream>>>(pre, proj_w, proj_b, out);
}